// Round 6
// baseline (275.405 us; speedup 1.0000x reference)
//
#include <hip/hip_runtime.h>

typedef __bf16 bf16_t;
typedef __bf16 bf16x8 __attribute__((ext_vector_type(8)));
typedef __bf16 bf16x4 __attribute__((ext_vector_type(4)));
typedef float f32x4 __attribute__((ext_vector_type(4)));

#define GLB_AS(p) ((const __attribute__((address_space(1))) unsigned int*)(p))
#define LDS_AS(p) ((__attribute__((address_space(3))) unsigned int*)(p))

// rows per KV-split = 16 bh * 2048 q = 32768; 4 splits of 512 kv each
#define SPLIT_ROWS 32768
// P-tile LDS row stride (32 + 2 pad) -> breaks row bank-alignment
#define PLD 34

// ---------------- fp32 -> bf16 convert (vectorized), optional scale ----------------
__global__ void cvt_bf16_kernel(const float* __restrict__ in, bf16_t* __restrict__ out, int n, float scale)
{
    int i = (blockIdx.x * blockDim.x + threadIdx.x) * 4;
    if (i >= n) return;
    float4 v = *(const float4*)(in + i);
    bf16x4 o;
    o[0] = (bf16_t)(v.x * scale); o[1] = (bf16_t)(v.y * scale);
    o[2] = (bf16_t)(v.z * scale); o[3] = (bf16_t)(v.w * scale);
    *(bf16x4*)(out + i) = o;
}

// ---------------- weight transpose: in f32 [R][C] -> out bf16 [C][R] ----------------
__global__ void wtrans_kernel(const float* __restrict__ in, bf16_t* __restrict__ out, int R, int C)
{
    __shared__ float tile[32][33];
    const int tid = threadIdx.x;
    const int r0 = blockIdx.y * 32, c0 = blockIdx.x * 32;
#pragma unroll
    for (int j = 0; j < 4; j++) {
        int r = j * 8 + (tid >> 5), c = tid & 31;
        tile[r][c] = in[(size_t)(r0 + r) * C + c0 + c];
    }
    __syncthreads();
#pragma unroll
    for (int j = 0; j < 4; j++) {
        int c = j * 8 + (tid >> 5), r = tid & 31;
        out[(size_t)(c0 + c) * R + r0 + r] = (bf16_t)tile[r][c];
    }
}

// ---------------- V transpose: QKV cols 1024..1535 -> Vt[bh][64][2048] ----------------
__global__ void vtrans_kernel(const bf16_t* __restrict__ qkv, bf16_t* __restrict__ vt)
{
    __shared__ bf16_t t[64][68];
    const int tid = threadIdx.x;
    const int lk0 = blockIdx.x * 64;
    const int bh = blockIdx.y, b = bh >> 3, h = bh & 7;
#pragma unroll
    for (int j = 0; j < 16; j++) {
        int e = j * 256 + tid;
        int lk_i = e >> 6, d = e & 63;
        t[lk_i][d] = qkv[(size_t)(b * 2048 + lk0 + lk_i) * 1536 + 1024 + h * 64 + d];
    }
    __syncthreads();
#pragma unroll
    for (int j = 0; j < 16; j++) {
        int e = j * 256 + tid;
        int d_i = e >> 6, lk = e & 63;
        vt[((size_t)bh * 64 + d_i) * 2048 + lk0 + lk] = t[lk][d_i];
    }
}

// ---------------- GEMM: C[M][N] = A[M][K] @ Bt[N][K]^T ----------------
// BM x 128 tile, BK=32, 256 threads / 4 waves (2x2 wave grid), global_load_lds width 16.
template<int BM, bool SPLITA, bool BIAS, bool RELU, bool OUTBF16>
__global__ __launch_bounds__(256)
void gemm_kernel(const bf16_t* __restrict__ A0, const bf16_t* __restrict__ A1, int nsplit,
                 const bf16_t* __restrict__ Bt, const float* __restrict__ bias,
                 void* __restrict__ Cout, int K, int ldC)
{
    constexpr int FR = BM / 32;  // A-frags per wave (wave owns BM/2 rows)
    __shared__ __align__(16) bf16_t As[BM * 32];
    __shared__ __align__(16) bf16_t Bs[128 * 32];
    const int bm = blockIdx.x, bn = blockIdx.y;
    const bf16_t* A = (!SPLITA || bn < nsplit) ? A0 : A1;
    const int tid = threadIdx.x;
    const int lane = tid & 63;
    const int wid = tid >> 6;
    const int wr = wid >> 1, wc = wid & 1;

    f32x4 acc[FR][4] = {};

    // B staging: 8 chunks of 1 KB, 2 per wave
    const int cb = wid * 2;
    const int lbB0 = cb * 1024 + lane * 16;
    const int rowB0 = lbB0 >> 6, colB0 = (lbB0 & 63) >> 1;
    const int rowB1 = (lbB0 + 1024) >> 6, colB1 = ((lbB0 + 1024) & 63) >> 1;
    // A staging: BM==128 -> 2 chunks/wave, BM==64 -> 1 chunk/wave
    const int lbA0 = (BM == 128 ? cb * 1024 : wid * 1024) + lane * 16;
    const int rowA0 = lbA0 >> 6, colA0 = (lbA0 & 63) >> 1;
    const int rowA1 = (lbA0 + 1024) >> 6, colA1 = ((lbA0 + 1024) & 63) >> 1;

    const bf16_t* Abase = A + (size_t)(bm * BM) * K;
    const bf16_t* Bbase = Bt + (size_t)(bn * 128) * K;

    for (int k0 = 0; k0 < K; k0 += 32) {
        if constexpr (BM == 128) {
            __builtin_amdgcn_global_load_lds(GLB_AS(Abase + (size_t)rowA0 * K + k0 + colA0), LDS_AS(As + cb * 512), 16, 0, 0);
            __builtin_amdgcn_global_load_lds(GLB_AS(Abase + (size_t)rowA1 * K + k0 + colA1), LDS_AS(As + cb * 512 + 512), 16, 0, 0);
        } else {
            __builtin_amdgcn_global_load_lds(GLB_AS(Abase + (size_t)rowA0 * K + k0 + colA0), LDS_AS(As + wid * 512), 16, 0, 0);
        }
        __builtin_amdgcn_global_load_lds(GLB_AS(Bbase + (size_t)rowB0 * K + k0 + colB0), LDS_AS(Bs + cb * 512), 16, 0, 0);
        __builtin_amdgcn_global_load_lds(GLB_AS(Bbase + (size_t)rowB1 * K + k0 + colB1), LDS_AS(Bs + cb * 512 + 512), 16, 0, 0);
        __syncthreads();
        bf16x8 af[FR], bfr[4];
#pragma unroll
        for (int f = 0; f < FR; f++)
            af[f] = *(const bf16x8*)&As[(wr * (BM / 2) + f * 16 + (lane & 15)) * 32 + (lane >> 4) * 8];
#pragma unroll
        for (int f = 0; f < 4; f++)
            bfr[f] = *(const bf16x8*)&Bs[(wc * 64 + f * 16 + (lane & 15)) * 32 + (lane >> 4) * 8];
#pragma unroll
        for (int fr = 0; fr < FR; fr++)
#pragma unroll
            for (int fc = 0; fc < 4; fc++)
                acc[fr][fc] = __builtin_amdgcn_mfma_f32_16x16x32_bf16(af[fr], bfr[fc], acc[fr][fc], 0, 0, 0);
        __syncthreads();
    }

    const int rg = (lane >> 4) * 4, cl = lane & 15;
#pragma unroll
    for (int fc = 0; fc < 4; fc++) {
        const int col = bn * 128 + wc * 64 + fc * 16 + cl;
        float bv = 0.f;
        if (BIAS) bv = bias[col];
#pragma unroll
        for (int fr = 0; fr < FR; fr++) {
#pragma unroll
            for (int r = 0; r < 4; r++) {
                int rowg = bm * BM + wr * (BM / 2) + fr * 16 + rg + r;
                float v = acc[fr][fc][r] + bv;
                if (RELU) v = fmaxf(v, 0.f);
                if (OUTBF16) ((bf16_t*)Cout)[(size_t)rowg * ldC + col] = (bf16_t)v;
                else         ((float*)Cout)[(size_t)rowg * ldC + col] = v;
            }
        }
    }
}

// ---------------- flash attention, 4-way KV-split, KVBLK=32, exp2-domain ----------------
__device__ __forceinline__ float rowmax16(float v)
{
    v = fmaxf(v, __shfl_xor(v, 1));
    v = fmaxf(v, __shfl_xor(v, 2));
    v = fmaxf(v, __shfl_xor(v, 4));
    v = fmaxf(v, __shfl_xor(v, 8));
    return v;
}

// grid (32 qblocks, 16 bh, 4 kv-splits); 4 waves x 16 q-rows = 64 q-rows/block.
// Each split covers 512 kv rows, KVBLK=32 -> 16 iterations.
// Q pre-scaled by 0.125*log2(e); all exps raw v_exp_f32; m in log2 units;
// row-sum via extra MFMA against an all-ones B fragment.
// launch_bounds(256, 8): force VGPR<=64 so 8 blocks/CU (32 waves/CU) are resident.
__global__ __launch_bounds__(256, 8)
void flash_kernel(const bf16_t* __restrict__ QKV, const bf16_t* __restrict__ Vt,
                  bf16_t* __restrict__ Op01, bf16_t* __restrict__ Op23,
                  float2* __restrict__ ml)
{
    const int tid = threadIdx.x, lane = tid & 63, wid = tid >> 6;
    const int bh = blockIdx.y, b = bh >> 3, h = bh & 7;
    const int split = blockIdx.z;
    const int qbase = blockIdx.x * 64 + wid * 16;   // q-row base of this wave (within bh)
    __shared__ __align__(16) bf16_t plds[4][16 * PLD];
    bf16_t* pw = &plds[wid][0];

    const int l15 = lane & 15, g = lane >> 4;
    const bf16_t* Qbase = QKV + (size_t)(b * 2048) * 1536 + h * 64;
    const bf16_t* Kbase = QKV + (size_t)(b * 2048) * 1536 + 512 + h * 64;
    const bf16_t* Vbase = Vt + (size_t)bh * 64 * 2048;

    bf16x8 qf[2];
#pragma unroll
    for (int t = 0; t < 2; t++)
        qf[t] = *(const bf16x8*)(Qbase + (size_t)(qbase + l15) * 1536 + t * 32 + g * 8);

    bf16x8 ones;
#pragma unroll
    for (int e = 0; e < 8; e++) ones[e] = (bf16_t)1.0f;

    float m[4];
    f32x4 acc[4] = {};
    f32x4 accs = {};
#pragma unroll
    for (int r = 0; r < 4; r++) m[r] = -1e30f;

    const int kv0 = split * 512;
    for (int kt = kv0; kt < kv0 + 512; kt += 32) {
        bf16x8 kf[2][2];
#pragma unroll
        for (int c = 0; c < 2; c++)
#pragma unroll
            for (int t = 0; t < 2; t++)
                kf[c][t] = *(const bf16x8*)(Kbase + (size_t)(kt + c * 16 + l15) * 1536 + t * 32 + g * 8);

        f32x4 s0 = {}, s1 = {};
        __builtin_amdgcn_s_setprio(1);
        s0 = __builtin_amdgcn_mfma_f32_16x16x32_bf16(qf[0], kf[0][0], s0, 0, 0, 0);
        s0 = __builtin_amdgcn_mfma_f32_16x16x32_bf16(qf[1], kf[0][1], s0, 0, 0, 0);
        s1 = __builtin_amdgcn_mfma_f32_16x16x32_bf16(qf[0], kf[1][0], s1, 0, 0, 0);
        s1 = __builtin_amdgcn_mfma_f32_16x16x32_bf16(qf[1], kf[1][1], s1, 0, 0, 0);
        __builtin_amdgcn_s_setprio(0);

        bf16x8 vf[4];
#pragma unroll
        for (int fc = 0; fc < 4; fc++)
            vf[fc] = *(const bf16x8*)(Vbase + (size_t)(fc * 16 + l15) * 2048 + kt + g * 8);

#pragma unroll
        for (int r = 0; r < 4; r++) {
            float a0 = s0[r], a1 = s1[r];
            float cm = rowmax16(fmaxf(a0, a1));
            float mold = m[r];
            float mnew = fmaxf(mold, cm);
            float fac = __builtin_amdgcn_exp2f(mold - mnew);
            m[r] = mnew;
            acc[0][r] *= fac; acc[1][r] *= fac;
            acc[2][r] *= fac; acc[3][r] *= fac;
            accs[r] *= fac;
            const int row = g * 4 + r;
            pw[row * PLD +      l15] = (bf16_t)__builtin_amdgcn_exp2f(a0 - mnew);
            pw[row * PLD + 16 + l15] = (bf16_t)__builtin_amdgcn_exp2f(a1 - mnew);
        }

        // same-wave DS ops are processed in order: writes above visible to reads below
        bf16x8 pa = *(const bf16x8*)&pw[l15 * PLD + g * 8];
        __builtin_amdgcn_s_setprio(1);
#pragma unroll
        for (int fc = 0; fc < 4; fc++)
            acc[fc] = __builtin_amdgcn_mfma_f32_16x16x32_bf16(pa, vf[fc], acc[fc], 0, 0, 0);
        accs = __builtin_amdgcn_mfma_f32_16x16x32_bf16(pa, ones, accs, 0, 0, 0);
        __builtin_amdgcn_s_setprio(0);
    }

    // write normalized bf16 partial + (m, l)
    bf16_t* Op = (split < 2) ? Op01 + (size_t)split * SPLIT_ROWS * 64
                             : Op23 + (size_t)(split - 2) * SPLIT_ROWS * 64;
#pragma unroll
    for (int r = 0; r < 4; r++) {
        const int qrow = qbase + g * 4 + r;
        const size_t prow = (size_t)bh * 2048 + qrow;
        float inv = 1.f / accs[r];
#pragma unroll
        for (int fc = 0; fc < 4; fc++)
            Op[prow * 64 + fc * 16 + l15] = (bf16_t)(acc[fc][r] * inv);
        if (l15 == 0) ml[(size_t)split * SPLIT_ROWS + prow] = make_float2(m[r], accs[r]);
    }
}

// ---------------- combine 4 KV-split partials -> O f32 [4096][512] ----------------
// 32768 rows x 64 dims = 2,097,152 threads = 8192 blocks x 256. m in log2 units.
__global__ __launch_bounds__(256)
void combine_kernel(const bf16_t* __restrict__ Op01, const bf16_t* __restrict__ Op23,
                    const float2* __restrict__ ml, float* __restrict__ O)
{
    int t = blockIdx.x * 256 + threadIdx.x;
    int dim = t & 63;
    int row = t >> 6;                          // bh*2048 + qrow, < 32768
    int bh = row >> 11, qrow = row & 2047;
    float2 m0 = ml[row];
    float2 m1 = ml[SPLIT_ROWS + row];
    float2 m2 = ml[2 * SPLIT_ROWS + row];
    float2 m3 = ml[3 * SPLIT_ROWS + row];
    float M = fmaxf(fmaxf(m0.x, m1.x), fmaxf(m2.x, m3.x));
    float w0 = m0.y * __builtin_amdgcn_exp2f(m0.x - M);
    float w1 = m1.y * __builtin_amdgcn_exp2f(m1.x - M);
    float w2 = m2.y * __builtin_amdgcn_exp2f(m2.x - M);
    float w3 = m3.y * __builtin_amdgcn_exp2f(m3.x - M);
    float o = (w0 * (float)Op01[(size_t)row * 64 + dim]
             + w1 * (float)Op01[(size_t)(SPLIT_ROWS + row) * 64 + dim]
             + w2 * (float)Op23[(size_t)row * 64 + dim]
             + w3 * (float)Op23[(size_t)(SPLIT_ROWS + row) * 64 + dim]) / (w0 + w1 + w2 + w3);
    int b = bh >> 3, h = bh & 7;
    O[((size_t)(b * 2048 + qrow)) * 512 + h * 64 + dim] = o;
}

// ---------------- fused residual-add + LayerNorm (D=512) ----------------
template<bool RESBF>
__global__ __launch_bounds__(128)
void add_ln_kernel(const float* __restrict__ a, const void* __restrict__ res,
                   const float* __restrict__ g, const float* __restrict__ bta,
                   float* outf, bf16_t* outb)
{
    const int row = blockIdx.x, tid = threadIdx.x;
    const float4* a4 = (const float4*)(a + (size_t)row * 512);
    float4 av = a4[tid];
    float r0, r1, r2, r3;
    if (RESBF) {
        bf16x4 rv = ((const bf16x4*)res)[row * 128 + tid];
        r0 = (float)rv[0]; r1 = (float)rv[1]; r2 = (float)rv[2]; r3 = (float)rv[3];
    } else {
        float4 rv = ((const float4*)res)[row * 128 + tid];
        r0 = rv.x; r1 = rv.y; r2 = rv.z; r3 = rv.w;
    }
    float x0 = av.x + r0, x1 = av.y + r1, x2 = av.z + r2, x3 = av.w + r3;
    float s = x0 + x1 + x2 + x3;
    float sq = x0 * x0 + x1 * x1 + x2 * x2 + x3 * x3;
#pragma unroll
    for (int d = 1; d < 64; d <<= 1) { s += __shfl_xor(s, d); sq += __shfl_xor(sq, d); }
    __shared__ float red[2][2];
    const int wid = tid >> 6;
    if ((tid & 63) == 0) { red[wid][0] = s; red[wid][1] = sq; }
    __syncthreads();
    s = red[0][0] + red[1][0];
    sq = red[0][1] + red[1][1];
    float mu = s * (1.f / 512.f);
    float var = sq * (1.f / 512.f) - mu * mu;
    float rstd = rsqrtf(var + 1e-5f);
    const float4* g4 = (const float4*)g;
    const float4* b4 = (const float4*)bta;
    float4 gv = g4[tid], bv = b4[tid];
    float4 y;
    y.x = (x0 - mu) * rstd * gv.x + bv.x;
    y.y = (x1 - mu) * rstd * gv.y + bv.y;
    y.z = (x2 - mu) * rstd * gv.z + bv.z;
    y.w = (x3 - mu) * rstd * gv.w + bv.w;
    if (outf) ((float4*)(outf + (size_t)row * 512))[tid] = y;
    if (outb) {
        bf16x4 o;
        o[0] = (bf16_t)y.x; o[1] = (bf16_t)y.y; o[2] = (bf16_t)y.z; o[3] = (bf16_t)y.w;
        *(bf16x4*)(outb + (size_t)row * 512 + tid * 4) = o;
    }
}

// ---------------- orchestration ----------------
// Workspace arena (29.5 MB high-water; lifetime-safe aliasing):
//   0- 2 MB : W1t    (A->F)
//   2- 4 MB : W2t    (A->G)
//   4-12 MB : Xb(4-8)+Eb(8-12) (A->B); then Opart splits 0-1 (D->D2); then out1b at 4-8 (E->H)
//  12-24 MB : QKVb   (B->D); then O f32 at 12-20 (D2->E); then Hb 12-28 (F->G)
//  24-28 MB : Vtb    (C->D); then Hb[12:16MB]   (F->G)
//  28-29.5  : Wqkvt  (A->B); then ml 1MB (4x32768 float2) (D->D2)
// d_out (16 MB): Opart splits 2-3 in first 8 MB (D->D2); then FF f32 (G->H, in-place LN2).
extern "C" void kernel_launch(void* const* d_in, const int* in_sizes, int n_in,
                              void* d_out, int out_size, void* d_ws, size_t ws_size,
                              hipStream_t stream)
{
    const float* inputs = (const float*)d_in[0];
    const float* encx   = (const float*)d_in[1];
    const float* Wq     = (const float*)d_in[2];
    const float* Wk     = (const float*)d_in[3];
    const float* Wv     = (const float*)d_in[4];
    const float* ln1g   = (const float*)d_in[5];
    const float* ln1b   = (const float*)d_in[6];
    const float* W1     = (const float*)d_in[7];
    const float* b1     = (const float*)d_in[8];
    const float* W2     = (const float*)d_in[9];
    const float* b2     = (const float*)d_in[10];
    const float* ln2g   = (const float*)d_in[11];
    const float* ln2b   = (const float*)d_in[12];

    char* ws = (char*)d_ws;
    const size_t MB = 1u << 20;
    bf16_t* W1t   = (bf16_t*)(ws);
    bf16_t* W2t   = (bf16_t*)(ws + 2 * MB);
    bf16_t* Xb    = (bf16_t*)(ws + 4 * MB);
    bf16_t* Op01  = (bf16_t*)(ws + 4 * MB);       // 8 MB, aliases Xb+Eb (dead after QKV gemm)
    bf16_t* out1b = (bf16_t*)(ws + 4 * MB);       // 4 MB, aliases Op01 (dead after combine)
    bf16_t* Eb    = (bf16_t*)(ws + 8 * MB);
    bf16_t* QKVb  = (bf16_t*)(ws + 12 * MB);
    float*  Obuf  = (float*)(ws + 12 * MB);       // 8 MB f32, aliases QKVb (dead after flash)
    bf16_t* Hb    = (bf16_t*)(ws + 12 * MB);      // 16 MB, aliases Obuf+Vtb (dead after F's deps)
    bf16_t* Vtb   = (bf16_t*)(ws + 24 * MB);
    bf16_t* Wqkvt = (bf16_t*)(ws + 28 * MB);
    float2* mlbuf = (float2*)(ws + 28 * MB);      // 1 MB, aliases Wqkvt (dead after QKV gemm)
    bf16_t* Op23  = (bf16_t*)d_out;               // 8 MB, d_out unused until combine
    float*  FF    = (float*)d_out;                // FF (G->H, consumed in-place by ln2)

    // A. converts + weight transposes.  Q path folds 0.125 * log2(e) (exp2 domain).
    cvt_bf16_kernel<<<2048, 256, 0, stream>>>(inputs, Xb, 2097152, 0.125f * 1.44269504f);
    cvt_bf16_kernel<<<2048, 256, 0, stream>>>(encx, Eb, 2097152, 1.0f);
    wtrans_kernel<<<dim3(16, 16), 256, 0, stream>>>(Wq, Wqkvt,              512, 512);
    wtrans_kernel<<<dim3(16, 16), 256, 0, stream>>>(Wk, Wqkvt + 512 * 512,  512, 512);
    wtrans_kernel<<<dim3(16, 16), 256, 0, stream>>>(Wv, Wqkvt + 1024 * 512, 512, 512);
    wtrans_kernel<<<dim3(64, 16), 256, 0, stream>>>(W1, W1t, 512, 2048);
    wtrans_kernel<<<dim3(16, 64), 256, 0, stream>>>(W2, W2t, 2048, 512);
    // B. fused QKV projection: C[4096][1536] (cols 0-511 Q from inputs, 512-1535 K,V from encoder)
    gemm_kernel<64, true, false, false, true><<<dim3(64, 12), 256, 0, stream>>>(
        Xb, Eb, 4, Wqkvt, nullptr, QKVb, 512, 1536);
    // C. V -> Vt[bh][64][2048]
    vtrans_kernel<<<dim3(32, 16), 256, 0, stream>>>(QKVb, Vtb);
    // D. flash attention (kv-split 4) -> bf16 partials + (m,l)
    flash_kernel<<<dim3(32, 16, 4), 256, 0, stream>>>(QKVb, Vtb, Op01, Op23, mlbuf);
    // D2. combine partials -> O f32 [4096][512] (over dead QKVb)
    combine_kernel<<<8192, 256, 0, stream>>>(Op01, Op23, mlbuf, Obuf);
    // E. out1 = LN(O + inputs) -> bf16 only
    add_ln_kernel<false><<<4096, 128, 0, stream>>>(Obuf, inputs, ln1g, ln1b, nullptr, out1b);
    // F. H = relu(out1 @ W1 + b1)  [4096][2048] bf16
    gemm_kernel<128, false, true, true, true><<<dim3(32, 16), 256, 0, stream>>>(
        out1b, nullptr, 0, W1t, b1, Hb, 512, 2048);
    // G. FF = H @ W2 + b2  [4096][512] f32 -> d_out
    gemm_kernel<64, false, true, false, false><<<dim3(64, 4), 256, 0, stream>>>(
        Hb, nullptr, 0, W2t, b2, FF, 2048, 512);
    // H. final = LN(FF + out1b) -> d_out (in-place, row-local)
    add_ln_kernel<true><<<4096, 128, 0, stream>>>(FF, out1b, ln2g, ln2b, (float*)d_out, nullptr);
}

// Round 7
// 203.715 us; speedup vs baseline: 1.3519x; 1.3519x over previous
//
#include <hip/hip_runtime.h>

typedef __bf16 bf16_t;
typedef __bf16 bf16x8 __attribute__((ext_vector_type(8)));
typedef __bf16 bf16x4 __attribute__((ext_vector_type(4)));
typedef float f32x4 __attribute__((ext_vector_type(4)));

#define GLB_AS(p) ((const __attribute__((address_space(1))) unsigned int*)(p))
#define LDS_AS(p) ((__attribute__((address_space(3))) unsigned int*)(p))

// rows per KV-split = 16 bh * 2048 q = 32768 (2 splits of 1024 kv each)
#define SPLIT_STRIDE 32768
// P-tile LDS row stride (32 + 2 pad)
#define PLD 34

// ---------------- fp32 -> bf16 convert (vectorized), optional scale ----------------
__global__ void cvt_bf16_kernel(const float* __restrict__ in, bf16_t* __restrict__ out, int n, float scale)
{
    int i = (blockIdx.x * blockDim.x + threadIdx.x) * 4;
    if (i >= n) return;
    float4 v = *(const float4*)(in + i);
    bf16x4 o;
    o[0] = (bf16_t)(v.x * scale); o[1] = (bf16_t)(v.y * scale);
    o[2] = (bf16_t)(v.z * scale); o[3] = (bf16_t)(v.w * scale);
    *(bf16x4*)(out + i) = o;
}

// ---------------- weight transpose: in f32 [R][C] -> out bf16 [C][R] ----------------
__global__ void wtrans_kernel(const float* __restrict__ in, bf16_t* __restrict__ out, int R, int C)
{
    __shared__ float tile[32][33];
    const int tid = threadIdx.x;
    const int r0 = blockIdx.y * 32, c0 = blockIdx.x * 32;
#pragma unroll
    for (int j = 0; j < 4; j++) {
        int r = j * 8 + (tid >> 5), c = tid & 31;
        tile[r][c] = in[(size_t)(r0 + r) * C + c0 + c];
    }
    __syncthreads();
#pragma unroll
    for (int j = 0; j < 4; j++) {
        int c = j * 8 + (tid >> 5), r = tid & 31;
        out[(size_t)(c0 + c) * R + r0 + r] = (bf16_t)tile[r][c];
    }
}

// ---------------- V transpose: QKV cols 1024..1535 -> Vt[bh][64][2048] ----------------
__global__ void vtrans_kernel(const bf16_t* __restrict__ qkv, bf16_t* __restrict__ vt)
{
    __shared__ bf16_t t[64][68];
    const int tid = threadIdx.x;
    const int lk0 = blockIdx.x * 64;
    const int bh = blockIdx.y, b = bh >> 3, h = bh & 7;
#pragma unroll
    for (int j = 0; j < 16; j++) {
        int e = j * 256 + tid;
        int lk_i = e >> 6, d = e & 63;
        t[lk_i][d] = qkv[(size_t)(b * 2048 + lk0 + lk_i) * 1536 + 1024 + h * 64 + d];
    }
    __syncthreads();
#pragma unroll
    for (int j = 0; j < 16; j++) {
        int e = j * 256 + tid;
        int d_i = e >> 6, lk = e & 63;
        vt[((size_t)bh * 64 + d_i) * 2048 + lk0 + lk] = t[lk][d_i];
    }
}

// ---------------- GEMM: C[M][N] = A[M][K] @ Bt[N][K]^T ----------------
template<int BM, bool SPLITA, bool BIAS, bool RELU, bool OUTBF16>
__global__ __launch_bounds__(256)
void gemm_kernel(const bf16_t* __restrict__ A0, const bf16_t* __restrict__ A1, int nsplit,
                 const bf16_t* __restrict__ Bt, const float* __restrict__ bias,
                 void* __restrict__ Cout, int K, int ldC)
{
    constexpr int FR = BM / 32;
    __shared__ __align__(16) bf16_t As[BM * 32];
    __shared__ __align__(16) bf16_t Bs[128 * 32];
    const int bm = blockIdx.x, bn = blockIdx.y;
    const bf16_t* A = (!SPLITA || bn < nsplit) ? A0 : A1;
    const int tid = threadIdx.x;
    const int lane = tid & 63;
    const int wid = tid >> 6;
    const int wr = wid >> 1, wc = wid & 1;

    f32x4 acc[FR][4] = {};

    const int cb = wid * 2;
    const int lbB0 = cb * 1024 + lane * 16;
    const int rowB0 = lbB0 >> 6, colB0 = (lbB0 & 63) >> 1;
    const int rowB1 = (lbB0 + 1024) >> 6, colB1 = ((lbB0 + 1024) & 63) >> 1;
    const int lbA0 = (BM == 128 ? cb * 1024 : wid * 1024) + lane * 16;
    const int rowA0 = lbA0 >> 6, colA0 = (lbA0 & 63) >> 1;
    const int rowA1 = (lbA0 + 1024) >> 6, colA1 = ((lbA0 + 1024) & 63) >> 1;

    const bf16_t* Abase = A + (size_t)(bm * BM) * K;
    const bf16_t* Bbase = Bt + (size_t)(bn * 128) * K;

    for (int k0 = 0; k0 < K; k0 += 32) {
        if constexpr (BM == 128) {
            __builtin_amdgcn_global_load_lds(GLB_AS(Abase + (size_t)rowA0 * K + k0 + colA0), LDS_AS(As + cb * 512), 16, 0, 0);
            __builtin_amdgcn_global_load_lds(GLB_AS(Abase + (size_t)rowA1 * K + k0 + colA1), LDS_AS(As + cb * 512 + 512), 16, 0, 0);
        } else {
            __builtin_amdgcn_global_load_lds(GLB_AS(Abase + (size_t)rowA0 * K + k0 + colA0), LDS_AS(As + wid * 512), 16, 0, 0);
        }
        __builtin_amdgcn_global_load_lds(GLB_AS(Bbase + (size_t)rowB0 * K + k0 + colB0), LDS_AS(Bs + cb * 512), 16, 0, 0);
        __builtin_amdgcn_global_load_lds(GLB_AS(Bbase + (size_t)rowB1 * K + k0 + colB1), LDS_AS(Bs + cb * 512 + 512), 16, 0, 0);
        __syncthreads();
        bf16x8 af[FR], bfr[4];
#pragma unroll
        for (int f = 0; f < FR; f++)
            af[f] = *(const bf16x8*)&As[(wr * (BM / 2) + f * 16 + (lane & 15)) * 32 + (lane >> 4) * 8];
#pragma unroll
        for (int f = 0; f < 4; f++)
            bfr[f] = *(const bf16x8*)&Bs[(wc * 64 + f * 16 + (lane & 15)) * 32 + (lane >> 4) * 8];
#pragma unroll
        for (int fr = 0; fr < FR; fr++)
#pragma unroll
            for (int fc = 0; fc < 4; fc++)
                acc[fr][fc] = __builtin_amdgcn_mfma_f32_16x16x32_bf16(af[fr], bfr[fc], acc[fr][fc], 0, 0, 0);
        __syncthreads();
    }

    const int rg = (lane >> 4) * 4, cl = lane & 15;
#pragma unroll
    for (int fc = 0; fc < 4; fc++) {
        const int col = bn * 128 + wc * 64 + fc * 16 + cl;
        float bv = 0.f;
        if (BIAS) bv = bias[col];
#pragma unroll
        for (int fr = 0; fr < FR; fr++) {
#pragma unroll
            for (int r = 0; r < 4; r++) {
                int rowg = bm * BM + wr * (BM / 2) + fr * 16 + rg + r;
                float v = acc[fr][fc][r] + bv;
                if (RELU) v = fmaxf(v, 0.f);
                if (OUTBF16) ((bf16_t*)Cout)[(size_t)rowg * ldC + col] = (bf16_t)v;
                else         ((float*)Cout)[(size_t)rowg * ldC + col] = v;
            }
        }
    }
}

// ---------------- flash attention: block-shared K/V LDS staging, 2-phase pipeline ----------------
__device__ __forceinline__ float rowmax16(float v)
{
    v = fmaxf(v, __shfl_xor(v, 1));
    v = fmaxf(v, __shfl_xor(v, 2));
    v = fmaxf(v, __shfl_xor(v, 4));
    v = fmaxf(v, __shfl_xor(v, 8));
    return v;
}

// grid (32 qblocks, 16 bh, 2 kv-splits); 4 waves x 16 q-rows; KVBLK=32 shared by all waves.
// K staged via global_load_lds: linear LDS dest + pre-swizzled global source; read applies
// byte ^ ((row&7)<<4)  (both-sides involution, rule 21). V reg-staged to padded [64][40]
// LDS tile (conflict-free b128 reads). One barrier per K-tile (T3-minimum 2-phase).
// Q pre-scaled by 0.125*log2(e); m in log2 units; row-sum via ones-MFMA.
__global__ __launch_bounds__(256)
void flash_kernel(const bf16_t* __restrict__ QKV, const bf16_t* __restrict__ Vt,
                  bf16_t* __restrict__ Opart, float2* __restrict__ ml)
{
    const int tid = threadIdx.x, lane = tid & 63, wid = tid >> 6;
    const int bh = blockIdx.y, b = bh >> 3, h = bh & 7;
    const int split = blockIdx.z;
    const int qbase = blockIdx.x * 64 + wid * 16;
    __shared__ __align__(16) bf16_t Ks[2][32 * 64];   // 4 KB each, swizzled content
    __shared__ __align__(16) bf16_t Vs[2][64 * 40];   // 5 KB each, padded rows (80B)
    __shared__ __align__(16) bf16_t plds[4][16 * PLD];
    bf16_t* pw = &plds[wid][0];

    const int l15 = lane & 15, g = lane >> 4;
    const bf16_t* Qbase = QKV + (size_t)(b * 2048) * 1536 + h * 64;
    const bf16_t* Kbase = QKV + (size_t)(b * 2048) * 1536 + 512 + h * 64;
    const bf16_t* Vbase = Vt + (size_t)bh * 64 * 2048;

    // staging lane geometry
    const int krow = lane >> 3;   // + j*8  (K tile row)
    const int kcol = lane & 7;    // 16B chunk index within 128B row (pre-swizzled vs row)
    const int vrow = lane >> 2;   // + j*16 (V tile row = d)
    const int vcol = lane & 3;    // 16B chunk within 64B of kv values

    bf16x8 qf[2];
#pragma unroll
    for (int t = 0; t < 2; t++)
        qf[t] = *(const bf16x8*)(Qbase + (size_t)(qbase + l15) * 1536 + t * 32 + g * 8);

    bf16x8 ones;
#pragma unroll
    for (int e = 0; e < 8; e++) ones[e] = (bf16_t)1.0f;

    float m[4];
    f32x4 acc[4] = {};
    f32x4 accs = {};
#pragma unroll
    for (int r = 0; r < 4; r++) m[r] = -1e30f;

    const int kv0 = split * 1024;
    bf16x8 vreg[4];

    // prologue: stage tile 0 into buf 0
    {
#pragma unroll
        for (int j = 0; j < 4; j++) {
            int row = j * 8 + krow;
            __builtin_amdgcn_global_load_lds(
                GLB_AS(Kbase + (size_t)(kv0 + row) * 1536 + (kcol ^ (row & 7)) * 8),
                LDS_AS(&Ks[0][j * 512]), 16, 0, 0);
        }
#pragma unroll
        for (int j = 0; j < 4; j++)
            vreg[j] = *(const bf16x8*)(Vbase + (size_t)(j * 16 + vrow) * 2048 + kv0 + vcol * 8);
#pragma unroll
        for (int j = 0; j < 4; j++)
            *(bf16x8*)&Vs[0][(j * 16 + vrow) * 40 + vcol * 8] = vreg[j];
        __syncthreads();  // drains vmcnt+lgkmcnt: K gload + V writes complete
    }

    int buf = 0;
    for (int kt = kv0; kt < kv0 + 1024; kt += 32) {
        const bool last = (kt + 32 >= kv0 + 1024);
        // phase 1: issue next tile's loads (hidden under compute below)
        if (!last) {
            const int kn = kt + 32;
#pragma unroll
            for (int j = 0; j < 4; j++) {
                int row = j * 8 + krow;
                __builtin_amdgcn_global_load_lds(
                    GLB_AS(Kbase + (size_t)(kn + row) * 1536 + (kcol ^ (row & 7)) * 8),
                    LDS_AS(&Ks[buf ^ 1][j * 512]), 16, 0, 0);
            }
#pragma unroll
            for (int j = 0; j < 4; j++)
                vreg[j] = *(const bf16x8*)(Vbase + (size_t)(j * 16 + vrow) * 2048 + kn + vcol * 8);
        }

        // phase 2: compute from buf
        bf16x8 kf[2][2];
#pragma unroll
        for (int c = 0; c < 2; c++)
#pragma unroll
            for (int t = 0; t < 2; t++) {
                int row = c * 16 + l15;
                int byteoff = row * 128 + ((t * 64 + g * 16) ^ ((row & 7) << 4));
                kf[c][t] = *(const bf16x8*)&Ks[buf][byteoff >> 1];
            }
        f32x4 s0 = {}, s1 = {};
        s0 = __builtin_amdgcn_mfma_f32_16x16x32_bf16(qf[0], kf[0][0], s0, 0, 0, 0);
        s0 = __builtin_amdgcn_mfma_f32_16x16x32_bf16(qf[1], kf[0][1], s0, 0, 0, 0);
        s1 = __builtin_amdgcn_mfma_f32_16x16x32_bf16(qf[0], kf[1][0], s1, 0, 0, 0);
        s1 = __builtin_amdgcn_mfma_f32_16x16x32_bf16(qf[1], kf[1][1], s1, 0, 0, 0);

        bf16x8 vf[4];
#pragma unroll
        for (int fc = 0; fc < 4; fc++)
            vf[fc] = *(const bf16x8*)&Vs[buf][(fc * 16 + l15) * 40 + g * 8];

#pragma unroll
        for (int r = 0; r < 4; r++) {
            float a0 = s0[r], a1 = s1[r];
            float cm = rowmax16(fmaxf(a0, a1));
            float mold = m[r];
            float mnew = fmaxf(mold, cm);
            float fac = __builtin_amdgcn_exp2f(mold - mnew);
            m[r] = mnew;
            acc[0][r] *= fac; acc[1][r] *= fac;
            acc[2][r] *= fac; acc[3][r] *= fac;
            accs[r] *= fac;
            const int row = g * 4 + r;
            pw[row * PLD +      l15] = (bf16_t)__builtin_amdgcn_exp2f(a0 - mnew);
            pw[row * PLD + 16 + l15] = (bf16_t)__builtin_amdgcn_exp2f(a1 - mnew);
        }

        // same-wave DS ordering: pw writes above visible to this read
        bf16x8 pa = *(const bf16x8*)&pw[l15 * PLD + g * 8];
#pragma unroll
        for (int fc = 0; fc < 4; fc++)
            acc[fc] = __builtin_amdgcn_mfma_f32_16x16x32_bf16(pa, vf[fc], acc[fc], 0, 0, 0);
        accs = __builtin_amdgcn_mfma_f32_16x16x32_bf16(pa, ones, accs, 0, 0, 0);

        // phase 3: commit next V tile (compiler waits vmcnt for vreg deps)
        if (!last) {
#pragma unroll
            for (int j = 0; j < 4; j++)
                *(bf16x8*)&Vs[buf ^ 1][(j * 16 + vrow) * 40 + vcol * 8] = vreg[j];
        }
        __syncthreads();  // one barrier per K-tile; drains K gload before next iter reads
        buf ^= 1;
    }

    // write normalized bf16 partial + (m, l)
#pragma unroll
    for (int r = 0; r < 4; r++) {
        const int qrow = qbase + g * 4 + r;
        const size_t prow = (size_t)split * SPLIT_STRIDE + (size_t)bh * 2048 + qrow;
        float inv = 1.f / accs[r];
#pragma unroll
        for (int fc = 0; fc < 4; fc++)
            Opart[prow * 64 + fc * 16 + l15] = (bf16_t)(acc[fc][r] * inv);
        if (l15 == 0) ml[prow] = make_float2(m[r], accs[r]);
    }
}

// ---------------- combine 2 KV-split partials -> O f32 [4096][512] ----------------
// 32768 rows x 64 dims; m in log2 units.
__global__ __launch_bounds__(256)
void combine_kernel(const bf16_t* __restrict__ Opart, const float2* __restrict__ ml,
                    float* __restrict__ O)
{
    int t = blockIdx.x * 256 + threadIdx.x;
    int dim = t & 63;
    int row = t >> 6;                          // bh*2048 + qrow, < 32768
    int bh = row >> 11, qrow = row & 2047;
    float2 ml0 = ml[row];
    float2 ml1 = ml[SPLIT_STRIDE + row];
    float M = fmaxf(ml0.x, ml1.x);
    float w0 = ml0.y * __builtin_amdgcn_exp2f(ml0.x - M);
    float w1 = ml1.y * __builtin_amdgcn_exp2f(ml1.x - M);
    float o = (w0 * (float)Opart[(size_t)row * 64 + dim]
             + w1 * (float)Opart[(size_t)(SPLIT_STRIDE + row) * 64 + dim]) / (w0 + w1);
    int b = bh >> 3, h = bh & 7;
    O[((size_t)(b * 2048 + qrow)) * 512 + h * 64 + dim] = o;
}

// ---------------- fused residual-add + LayerNorm (D=512) ----------------
template<bool RESBF>
__global__ __launch_bounds__(128)
void add_ln_kernel(const float* __restrict__ a, const void* __restrict__ res,
                   const float* __restrict__ g, const float* __restrict__ bta,
                   float* outf, bf16_t* outb)
{
    const int row = blockIdx.x, tid = threadIdx.x;
    const float4* a4 = (const float4*)(a + (size_t)row * 512);
    float4 av = a4[tid];
    float r0, r1, r2, r3;
    if (RESBF) {
        bf16x4 rv = ((const bf16x4*)res)[row * 128 + tid];
        r0 = (float)rv[0]; r1 = (float)rv[1]; r2 = (float)rv[2]; r3 = (float)rv[3];
    } else {
        float4 rv = ((const float4*)res)[row * 128 + tid];
        r0 = rv.x; r1 = rv.y; r2 = rv.z; r3 = rv.w;
    }
    float x0 = av.x + r0, x1 = av.y + r1, x2 = av.z + r2, x3 = av.w + r3;
    float s = x0 + x1 + x2 + x3;
    float sq = x0 * x0 + x1 * x1 + x2 * x2 + x3 * x3;
#pragma unroll
    for (int d = 1; d < 64; d <<= 1) { s += __shfl_xor(s, d); sq += __shfl_xor(sq, d); }
    __shared__ float red[2][2];
    const int wid = tid >> 6;
    if ((tid & 63) == 0) { red[wid][0] = s; red[wid][1] = sq; }
    __syncthreads();
    s = red[0][0] + red[1][0];
    sq = red[0][1] + red[1][1];
    float mu = s * (1.f / 512.f);
    float var = sq * (1.f / 512.f) - mu * mu;
    float rstd = rsqrtf(var + 1e-5f);
    const float4* g4 = (const float4*)g;
    const float4* b4 = (const float4*)bta;
    float4 gv = g4[tid], bv = b4[tid];
    float4 y;
    y.x = (x0 - mu) * rstd * gv.x + bv.x;
    y.y = (x1 - mu) * rstd * gv.y + bv.y;
    y.z = (x2 - mu) * rstd * gv.z + bv.z;
    y.w = (x3 - mu) * rstd * gv.w + bv.w;
    if (outf) ((float4*)(outf + (size_t)row * 512))[tid] = y;
    if (outb) {
        bf16x4 o;
        o[0] = (bf16_t)y.x; o[1] = (bf16_t)y.y; o[2] = (bf16_t)y.z; o[3] = (bf16_t)y.w;
        *(bf16x4*)(outb + (size_t)row * 512 + tid * 4) = o;
    }
}

// ---------------- orchestration ----------------
// Workspace arena (29.5 MB high-water; lifetime-safe aliasing) — same as R4 (verified):
//   0- 2 MB : W1t    (A->F)
//   2- 4 MB : W2t    (A->G)
//   4-12 MB : Xb+Eb  (A->B)  then Opart (8 MB) (D->D2); out1b at 4-8 (E->H)
//  12-24 MB : QKVb   (B->D)  then Hb[0:12MB]   (F->G)
//  24-28 MB : Vtb    (C->D)  then Hb[12:16MB]  (F->G)
//  28-29.5  : Wqkvt  (A->B)  then ml (512 KB)  (D->D2)
// d_out (8 MB f32) doubles as O (D2->E) and FF (G->H, consumed in-place by LN2).
extern "C" void kernel_launch(void* const* d_in, const int* in_sizes, int n_in,
                              void* d_out, int out_size, void* d_ws, size_t ws_size,
                              hipStream_t stream)
{
    const float* inputs = (const float*)d_in[0];
    const float* encx   = (const float*)d_in[1];
    const float* Wq     = (const float*)d_in[2];
    const float* Wk     = (const float*)d_in[3];
    const float* Wv     = (const float*)d_in[4];
    const float* ln1g   = (const float*)d_in[5];
    const float* ln1b   = (const float*)d_in[6];
    const float* W1     = (const float*)d_in[7];
    const float* b1     = (const float*)d_in[8];
    const float* W2     = (const float*)d_in[9];
    const float* b2     = (const float*)d_in[10];
    const float* ln2g   = (const float*)d_in[11];
    const float* ln2b   = (const float*)d_in[12];

    char* ws = (char*)d_ws;
    const size_t MB = 1u << 20;
    bf16_t* W1t   = (bf16_t*)(ws);
    bf16_t* W2t   = (bf16_t*)(ws + 2 * MB);
    bf16_t* Xb    = (bf16_t*)(ws + 4 * MB);
    bf16_t* Opart = (bf16_t*)(ws + 4 * MB);       // 8 MB, aliases Xb+Eb (dead after QKV gemm)
    bf16_t* out1b = (bf16_t*)(ws + 4 * MB);       // 4 MB, aliases Opart[0:4] (dead after combine)
    bf16_t* Eb    = (bf16_t*)(ws + 8 * MB);
    bf16_t* QKVb  = (bf16_t*)(ws + 12 * MB);
    bf16_t* Hb    = (bf16_t*)(ws + 12 * MB);      // aliases QKVb+Vtb (dead after flash)
    bf16_t* Vtb   = (bf16_t*)(ws + 24 * MB);
    bf16_t* Wqkvt = (bf16_t*)(ws + 28 * MB);
    float2* mlbuf = (float2*)(ws + 28 * MB);      // 512 KB, aliases Wqkvt (dead after QKV gemm)
    float*  Obuf  = (float*)d_out;                // O (dead after ln1)
    float*  FF    = (float*)d_out;                // FF (consumed in-place by ln2)

    // A. converts + weight transposes.  Q path folds 0.125 * log2(e) (exp2 domain).
    cvt_bf16_kernel<<<2048, 256, 0, stream>>>(inputs, Xb, 2097152, 0.125f * 1.44269504f);
    cvt_bf16_kernel<<<2048, 256, 0, stream>>>(encx, Eb, 2097152, 1.0f);
    wtrans_kernel<<<dim3(16, 16), 256, 0, stream>>>(Wq, Wqkvt,              512, 512);
    wtrans_kernel<<<dim3(16, 16), 256, 0, stream>>>(Wk, Wqkvt + 512 * 512,  512, 512);
    wtrans_kernel<<<dim3(16, 16), 256, 0, stream>>>(Wv, Wqkvt + 1024 * 512, 512, 512);
    wtrans_kernel<<<dim3(64, 16), 256, 0, stream>>>(W1, W1t, 512, 2048);
    wtrans_kernel<<<dim3(16, 64), 256, 0, stream>>>(W2, W2t, 2048, 512);
    // B. fused QKV projection: C[4096][1536] (cols 0-511 Q from inputs, 512-1535 K,V from encoder)
    gemm_kernel<64, true, false, false, true><<<dim3(64, 12), 256, 0, stream>>>(
        Xb, Eb, 4, Wqkvt, nullptr, QKVb, 512, 1536);
    // C. V -> Vt[bh][64][2048]
    vtrans_kernel<<<dim3(32, 16), 256, 0, stream>>>(QKVb, Vtb);
    // D. flash attention (kv-split 2) -> bf16 partials + (m,l)
    flash_kernel<<<dim3(32, 16, 2), 256, 0, stream>>>(QKVb, Vtb, Opart, mlbuf);
    // D2. combine partials -> O (= d_out) f32 [4096][512]
    combine_kernel<<<8192, 256, 0, stream>>>(Opart, mlbuf, Obuf);
    // E. out1 = LN(O + inputs) -> bf16 only
    add_ln_kernel<false><<<4096, 128, 0, stream>>>(Obuf, inputs, ln1g, ln1b, nullptr, out1b);
    // F. H = relu(out1 @ W1 + b1)  [4096][2048] bf16
    gemm_kernel<128, false, true, true, true><<<dim3(32, 16), 256, 0, stream>>>(
        out1b, nullptr, 0, W1t, b1, Hb, 512, 2048);
    // G. FF = H @ W2 + b2  [4096][512] f32 -> d_out
    gemm_kernel<64, false, true, false, false><<<dim3(64, 4), 256, 0, stream>>>(
        Hb, nullptr, 0, W2t, b2, FF, 2048, 512);
    // H. final = LN(FF + out1b) -> d_out (in-place, row-local)
    add_ln_kernel<true><<<4096, 128, 0, stream>>>(FF, out1b, ln2g, ln2b, (float*)d_out, nullptr);
}

// Round 8
// 181.717 us; speedup vs baseline: 1.5156x; 1.1211x over previous
//
#include <hip/hip_runtime.h>

typedef __bf16 bf16_t;
typedef __bf16 bf16x8 __attribute__((ext_vector_type(8)));
typedef __bf16 bf16x4 __attribute__((ext_vector_type(4)));
typedef float f32x4 __attribute__((ext_vector_type(4)));
typedef float f32x16 __attribute__((ext_vector_type(16)));
typedef unsigned int u32;

#define GLB_AS(p) ((const __attribute__((address_space(1))) unsigned int*)(p))
#define LDS_AS(p) ((__attribute__((address_space(3))) unsigned int*)(p))

// rows per KV-split = 16 bh * 2048 q = 32768; 4 splits of 512 kv each
#define SPLIT_ROWS 32768

// ---------------- fp32 -> bf16 convert (vectorized), optional scale ----------------
__global__ void cvt_bf16_kernel(const float* __restrict__ in, bf16_t* __restrict__ out, int n, float scale)
{
    int i = (blockIdx.x * blockDim.x + threadIdx.x) * 4;
    if (i >= n) return;
    float4 v = *(const float4*)(in + i);
    bf16x4 o;
    o[0] = (bf16_t)(v.x * scale); o[1] = (bf16_t)(v.y * scale);
    o[2] = (bf16_t)(v.z * scale); o[3] = (bf16_t)(v.w * scale);
    *(bf16x4*)(out + i) = o;
}

// ---------------- weight transpose: in f32 [R][C] -> out bf16 [C][R] ----------------
__global__ void wtrans_kernel(const float* __restrict__ in, bf16_t* __restrict__ out, int R, int C)
{
    __shared__ float tile[32][33];
    const int tid = threadIdx.x;
    const int r0 = blockIdx.y * 32, c0 = blockIdx.x * 32;
#pragma unroll
    for (int j = 0; j < 4; j++) {
        int r = j * 8 + (tid >> 5), c = tid & 31;
        tile[r][c] = in[(size_t)(r0 + r) * C + c0 + c];
    }
    __syncthreads();
#pragma unroll
    for (int j = 0; j < 4; j++) {
        int c = j * 8 + (tid >> 5), r = tid & 31;
        out[(size_t)(c0 + c) * R + r0 + r] = (bf16_t)tile[r][c];
    }
}

// ---------------- V transpose: QKV cols 1024..1535 -> Vt[bh][64][2048] ----------------
__global__ void vtrans_kernel(const bf16_t* __restrict__ qkv, bf16_t* __restrict__ vt)
{
    __shared__ bf16_t t[64][68];
    const int tid = threadIdx.x;
    const int lk0 = blockIdx.x * 64;
    const int bh = blockIdx.y, b = bh >> 3, h = bh & 7;
#pragma unroll
    for (int j = 0; j < 16; j++) {
        int e = j * 256 + tid;
        int lk_i = e >> 6, d = e & 63;
        t[lk_i][d] = qkv[(size_t)(b * 2048 + lk0 + lk_i) * 1536 + 1024 + h * 64 + d];
    }
    __syncthreads();
#pragma unroll
    for (int j = 0; j < 16; j++) {
        int e = j * 256 + tid;
        int d_i = e >> 6, lk = e & 63;
        vt[((size_t)bh * 64 + d_i) * 2048 + lk0 + lk] = t[lk][d_i];
    }
}

// ---------------- GEMM: C[M][N] = A[M][K] @ Bt[N][K]^T ----------------
template<int BM, bool SPLITA, bool BIAS, bool RELU, bool OUTBF16>
__global__ __launch_bounds__(256)
void gemm_kernel(const bf16_t* __restrict__ A0, const bf16_t* __restrict__ A1, int nsplit,
                 const bf16_t* __restrict__ Bt, const float* __restrict__ bias,
                 void* __restrict__ Cout, int K, int ldC)
{
    constexpr int FR = BM / 32;
    __shared__ __align__(16) bf16_t As[BM * 32];
    __shared__ __align__(16) bf16_t Bs[128 * 32];
    const int bm = blockIdx.x, bn = blockIdx.y;
    const bf16_t* A = (!SPLITA || bn < nsplit) ? A0 : A1;
    const int tid = threadIdx.x;
    const int lane = tid & 63;
    const int wid = tid >> 6;
    const int wr = wid >> 1, wc = wid & 1;

    f32x4 acc[FR][4] = {};

    const int cb = wid * 2;
    const int lbB0 = cb * 1024 + lane * 16;
    const int rowB0 = lbB0 >> 6, colB0 = (lbB0 & 63) >> 1;
    const int rowB1 = (lbB0 + 1024) >> 6, colB1 = ((lbB0 + 1024) & 63) >> 1;
    const int lbA0 = (BM == 128 ? cb * 1024 : wid * 1024) + lane * 16;
    const int rowA0 = lbA0 >> 6, colA0 = (lbA0 & 63) >> 1;
    const int rowA1 = (lbA0 + 1024) >> 6, colA1 = ((lbA0 + 1024) & 63) >> 1;

    const bf16_t* Abase = A + (size_t)(bm * BM) * K;
    const bf16_t* Bbase = Bt + (size_t)(bn * 128) * K;

    for (int k0 = 0; k0 < K; k0 += 32) {
        if constexpr (BM == 128) {
            __builtin_amdgcn_global_load_lds(GLB_AS(Abase + (size_t)rowA0 * K + k0 + colA0), LDS_AS(As + cb * 512), 16, 0, 0);
            __builtin_amdgcn_global_load_lds(GLB_AS(Abase + (size_t)rowA1 * K + k0 + colA1), LDS_AS(As + cb * 512 + 512), 16, 0, 0);
        } else {
            __builtin_amdgcn_global_load_lds(GLB_AS(Abase + (size_t)rowA0 * K + k0 + colA0), LDS_AS(As + wid * 512), 16, 0, 0);
        }
        __builtin_amdgcn_global_load_lds(GLB_AS(Bbase + (size_t)rowB0 * K + k0 + colB0), LDS_AS(Bs + cb * 512), 16, 0, 0);
        __builtin_amdgcn_global_load_lds(GLB_AS(Bbase + (size_t)rowB1 * K + k0 + colB1), LDS_AS(Bs + cb * 512 + 512), 16, 0, 0);
        __syncthreads();
        bf16x8 af[FR], bfr[4];
#pragma unroll
        for (int f = 0; f < FR; f++)
            af[f] = *(const bf16x8*)&As[(wr * (BM / 2) + f * 16 + (lane & 15)) * 32 + (lane >> 4) * 8];
#pragma unroll
        for (int f = 0; f < 4; f++)
            bfr[f] = *(const bf16x8*)&Bs[(wc * 64 + f * 16 + (lane & 15)) * 32 + (lane >> 4) * 8];
#pragma unroll
        for (int fr = 0; fr < FR; fr++)
#pragma unroll
            for (int fc = 0; fc < 4; fc++)
                acc[fr][fc] = __builtin_amdgcn_mfma_f32_16x16x32_bf16(af[fr], bfr[fc], acc[fr][fc], 0, 0, 0);
        __syncthreads();
    }

    const int rg = (lane >> 4) * 4, cl = lane & 15;
#pragma unroll
    for (int fc = 0; fc < 4; fc++) {
        const int col = bn * 128 + wc * 64 + fc * 16 + cl;
        float bv = 0.f;
        if (BIAS) bv = bias[col];
#pragma unroll
        for (int fr = 0; fr < FR; fr++) {
#pragma unroll
            for (int r = 0; r < 4; r++) {
                int rowg = bm * BM + wr * (BM / 2) + fr * 16 + rg + r;
                float v = acc[fr][fc][r] + bv;
                if (RELU) v = fmaxf(v, 0.f);
                if (OUTBF16) ((bf16_t*)Cout)[(size_t)rowg * ldC + col] = (bf16_t)v;
                else         ((float*)Cout)[(size_t)rowg * ldC + col] = v;
            }
        }
    }
}

// ---------------- flash attention: swapped-QK^T 32x32, in-register softmax ----------------
union BU { bf16x8 v; u32 d[4]; };

static __device__ __forceinline__ u32 pkbf(float a, float b)
{
    union { bf16_t h[2]; u32 w; } u;
    u.h[0] = (bf16_t)a; u.h[1] = (bf16_t)b;
    return u.w;
}

// grid (16 qblocks, 16 bh, 4 kv-splits); 4 waves x 32 q-rows = 128 q/block; KVBLK=32.
// P = mfma(K_rows, Q_rows): P[kv on reg axis][q on lane axis] -> softmax is in-register
// (15-fmax tree + 1 shfl_xor(32)); P->bf16 pack + 8 shfl_xor(32) assembles the PV
// B-fragment; O^T[d][q] = mfma(Vt_rows, P_frag) accumulates in registers.
// C-row map (m74/m101): row = (reg&3) + 8*(reg>>2) + 4*(lane>>5).
// Q pre-scaled by 0.125*log2(e); m in log2 units; T13 defer-rescale (THR=12 log2 units).
// Epilogue: wave-private LDS transpose -> coalesced Opart[q][d] writes.
__global__ __launch_bounds__(256)
void flash_kernel(const bf16_t* __restrict__ QKV, const bf16_t* __restrict__ Vt,
                  bf16_t* __restrict__ Op01, bf16_t* __restrict__ Op23,
                  float2* __restrict__ ml)
{
    const int tid = threadIdx.x, lane = tid & 63, wid = tid >> 6;
    const int bh = blockIdx.y, b = bh >> 3, h = bh & 7;
    const int split = blockIdx.z;
    const int qbase = blockIdx.x * 128 + wid * 32;
    const int l31 = lane & 31, hi = lane >> 5;

    __shared__ __align__(16) bf16_t tlds[4][32 * 68];
    bf16_t* tw = &tlds[wid][0];

    const bf16_t* Qp = QKV + (size_t)(b * 2048 + qbase + l31) * 1536 + h * 64 + hi * 8;
    const bf16_t* Kp = QKV + (size_t)(b * 2048) * 1536 + 512 + h * 64 + hi * 8;
    const bf16_t* Vp = Vt + ((size_t)bh * 64 + l31) * 2048 + hi * 8;

    bf16x8 qf[4];
#pragma unroll
    for (int t = 0; t < 4; t++)
        qf[t] = *(const bf16x8*)(Qp + t * 16);

    f32x16 acc0 = {}, acc1 = {};
    float mrun = -1e30f, lsum = 0.f;

    const int kv0 = split * 512;
#pragma unroll 2
    for (int kt = kv0; kt < kv0 + 512; kt += 32) {
        // K A-fragments (rows = kv), V A-fragments (rows = d), contiguous 16B loads
        bf16x8 kf[4];
#pragma unroll
        for (int t = 0; t < 4; t++)
            kf[t] = *(const bf16x8*)(Kp + (size_t)(kt + l31) * 1536 + t * 16);
        bf16x8 vf00 = *(const bf16x8*)(Vp + kt);
        bf16x8 vf01 = *(const bf16x8*)(Vp + kt + 16);
        bf16x8 vf10 = *(const bf16x8*)(Vp + 32 * 2048 + kt);
        bf16x8 vf11 = *(const bf16x8*)(Vp + 32 * 2048 + kt + 16);

        // QK^T swapped: p[reg=kv][lane=q]
        f32x16 p = {};
        __builtin_amdgcn_s_setprio(1);
        p = __builtin_amdgcn_mfma_f32_32x32x16_bf16(kf[0], qf[0], p, 0, 0, 0);
        p = __builtin_amdgcn_mfma_f32_32x32x16_bf16(kf[1], qf[1], p, 0, 0, 0);
        p = __builtin_amdgcn_mfma_f32_32x32x16_bf16(kf[2], qf[2], p, 0, 0, 0);
        p = __builtin_amdgcn_mfma_f32_32x32x16_bf16(kf[3], qf[3], p, 0, 0, 0);
        __builtin_amdgcn_s_setprio(0);

        // tile max: balanced in-register tree + one cross-half exchange
        float x0 = fmaxf(p[0], p[8]),  x1 = fmaxf(p[1], p[9]);
        float x2 = fmaxf(p[2], p[10]), x3 = fmaxf(p[3], p[11]);
        float x4 = fmaxf(p[4], p[12]), x5 = fmaxf(p[5], p[13]);
        float x6 = fmaxf(p[6], p[14]), x7 = fmaxf(p[7], p[15]);
        x0 = fmaxf(x0, x4); x1 = fmaxf(x1, x5); x2 = fmaxf(x2, x6); x3 = fmaxf(x3, x7);
        float cm = fmaxf(fmaxf(x0, x1), fmaxf(x2, x3));
        cm = fmaxf(cm, __shfl_xor(cm, 32));

        // T13 defer-rescale: only rescale when the max actually grows
        if (__any(cm > mrun + 12.0f)) {
            float mnew = fmaxf(mrun, cm);
            float fac = __builtin_amdgcn_exp2f(mrun - mnew);
#pragma unroll
            for (int i = 0; i < 16; i++) { acc0[i] *= fac; acc1[i] *= fac; }
            lsum *= fac;
            mrun = mnew;
        }

        // exponentials (log2 domain)
        float e[16];
#pragma unroll
        for (int i = 0; i < 16; i++) e[i] = __builtin_amdgcn_exp2f(p[i] - mrun);

        // tile sum: in-register tree + one cross-half exchange
        float s0 = (e[0] + e[8]) + (e[1] + e[9]);
        float s1 = (e[2] + e[10]) + (e[3] + e[11]);
        float s2 = (e[4] + e[12]) + (e[5] + e[13]);
        float s3 = (e[6] + e[14]) + (e[7] + e[15]);
        float ts = (s0 + s1) + (s2 + s3);
        ts += __shfl_xor(ts, 32);
        lsum += ts;

        // pack to bf16 pairs (consecutive kv) and exchange halves for B-fragments
        u32 pk0 = pkbf(e[0], e[1]),   pk1 = pkbf(e[2], e[3]);
        u32 pk2 = pkbf(e[4], e[5]),   pk3 = pkbf(e[6], e[7]);
        u32 pk4 = pkbf(e[8], e[9]),   pk5 = pkbf(e[10], e[11]);
        u32 pk6 = pkbf(e[12], e[13]), pk7 = pkbf(e[14], e[15]);
        u32 s0w = __shfl_xor(pk0, 32), s1w = __shfl_xor(pk1, 32);
        u32 s2w = __shfl_xor(pk2, 32), s3w = __shfl_xor(pk3, 32);
        u32 s4w = __shfl_xor(pk4, 32), s5w = __shfl_xor(pk5, 32);
        u32 s6w = __shfl_xor(pk6, 32), s7w = __shfl_xor(pk7, 32);

        BU b0, b1;
        b0.d[0] = hi ? s2w : pk0;  b0.d[1] = hi ? s3w : pk1;
        b0.d[2] = hi ? pk2 : s0w;  b0.d[3] = hi ? pk3 : s1w;
        b1.d[0] = hi ? s6w : pk4;  b1.d[1] = hi ? s7w : pk5;
        b1.d[2] = hi ? pk6 : s4w;  b1.d[3] = hi ? pk7 : s5w;

        // PV: acc[T] += Vt_rows . P  -> O^T[d][q]
        __builtin_amdgcn_s_setprio(1);
        acc0 = __builtin_amdgcn_mfma_f32_32x32x16_bf16(vf00, b0.v, acc0, 0, 0, 0);
        acc0 = __builtin_amdgcn_mfma_f32_32x32x16_bf16(vf01, b1.v, acc0, 0, 0, 0);
        acc1 = __builtin_amdgcn_mfma_f32_32x32x16_bf16(vf10, b0.v, acc1, 0, 0, 0);
        acc1 = __builtin_amdgcn_mfma_f32_32x32x16_bf16(vf11, b1.v, acc1, 0, 0, 0);
        __builtin_amdgcn_s_setprio(0);
    }

    // epilogue: normalize, wave-private LDS transpose, coalesced writes
    float inv = 1.f / lsum;
#pragma unroll
    for (int r = 0; r < 16; r++) {
        int drow = (r & 3) + 8 * (r >> 2) + 4 * hi;
        tw[l31 * 68 + drow]      = (bf16_t)(acc0[r] * inv);
        tw[l31 * 68 + 32 + drow] = (bf16_t)(acc1[r] * inv);
    }
    // same-wave DS ordering: writes above visible to reads below (wave-private tile)
    bf16_t* Op = (split < 2) ? Op01 + (size_t)split * SPLIT_ROWS * 64
                             : Op23 + (size_t)(split - 2) * SPLIT_ROWS * 64;
    const size_t rowbase = (size_t)bh * 2048 + qbase;
#pragma unroll
    for (int ps = 0; ps < 4; ps++) {
        int rr = (lane >> 3) + ps * 8;
        int cc = lane & 7;
        bf16x8 ov = *(const bf16x8*)&tw[rr * 68 + cc * 8];
        *(bf16x8*)(Op + (rowbase + rr) * 64 + cc * 8) = ov;
    }
    if (lane < 32)
        ml[(size_t)split * SPLIT_ROWS + rowbase + l31] = make_float2(mrun, lsum);
}

// ---------------- combine 4 KV-split partials -> O f32 [4096][512] ----------------
// 32768 rows x 64 dims = 8192 blocks x 256. m in log2 units.
__global__ __launch_bounds__(256)
void combine_kernel(const bf16_t* __restrict__ Op01, const bf16_t* __restrict__ Op23,
                    const float2* __restrict__ ml, float* __restrict__ O)
{
    int t = blockIdx.x * 256 + threadIdx.x;
    int dim = t & 63;
    int row = t >> 6;                          // bh*2048 + qrow, < 32768
    int bh = row >> 11, qrow = row & 2047;
    float2 m0 = ml[row];
    float2 m1 = ml[SPLIT_ROWS + row];
    float2 m2 = ml[2 * SPLIT_ROWS + row];
    float2 m3 = ml[3 * SPLIT_ROWS + row];
    float M = fmaxf(fmaxf(m0.x, m1.x), fmaxf(m2.x, m3.x));
    float w0 = m0.y * __builtin_amdgcn_exp2f(m0.x - M);
    float w1 = m1.y * __builtin_amdgcn_exp2f(m1.x - M);
    float w2 = m2.y * __builtin_amdgcn_exp2f(m2.x - M);
    float w3 = m3.y * __builtin_amdgcn_exp2f(m3.x - M);
    float o = (w0 * (float)Op01[(size_t)row * 64 + dim]
             + w1 * (float)Op01[(size_t)(SPLIT_ROWS + row) * 64 + dim]
             + w2 * (float)Op23[(size_t)row * 64 + dim]
             + w3 * (float)Op23[(size_t)(SPLIT_ROWS + row) * 64 + dim]) / (w0 + w1 + w2 + w3);
    int b = bh >> 3, h = bh & 7;
    O[((size_t)(b * 2048 + qrow)) * 512 + h * 64 + dim] = o;
}

// ---------------- fused residual-add + LayerNorm (D=512) ----------------
template<bool RESBF>
__global__ __launch_bounds__(128)
void add_ln_kernel(const float* __restrict__ a, const void* __restrict__ res,
                   const float* __restrict__ g, const float* __restrict__ bta,
                   float* outf, bf16_t* outb)
{
    const int row = blockIdx.x, tid = threadIdx.x;
    const float4* a4 = (const float4*)(a + (size_t)row * 512);
    float4 av = a4[tid];
    float r0, r1, r2, r3;
    if (RESBF) {
        bf16x4 rv = ((const bf16x4*)res)[row * 128 + tid];
        r0 = (float)rv[0]; r1 = (float)rv[1]; r2 = (float)rv[2]; r3 = (float)rv[3];
    } else {
        float4 rv = ((const float4*)res)[row * 128 + tid];
        r0 = rv.x; r1 = rv.y; r2 = rv.z; r3 = rv.w;
    }
    float x0 = av.x + r0, x1 = av.y + r1, x2 = av.z + r2, x3 = av.w + r3;
    float s = x0 + x1 + x2 + x3;
    float sq = x0 * x0 + x1 * x1 + x2 * x2 + x3 * x3;
#pragma unroll
    for (int d = 1; d < 64; d <<= 1) { s += __shfl_xor(s, d); sq += __shfl_xor(sq, d); }
    __shared__ float red[2][2];
    const int wid = tid >> 6;
    if ((tid & 63) == 0) { red[wid][0] = s; red[wid][1] = sq; }
    __syncthreads();
    s = red[0][0] + red[1][0];
    sq = red[0][1] + red[1][1];
    float mu = s * (1.f / 512.f);
    float var = sq * (1.f / 512.f) - mu * mu;
    float rstd = rsqrtf(var + 1e-5f);
    const float4* g4 = (const float4*)g;
    const float4* b4 = (const float4*)bta;
    float4 gv = g4[tid], bv = b4[tid];
    float4 y;
    y.x = (x0 - mu) * rstd * gv.x + bv.x;
    y.y = (x1 - mu) * rstd * gv.y + bv.y;
    y.z = (x2 - mu) * rstd * gv.z + bv.z;
    y.w = (x3 - mu) * rstd * gv.w + bv.w;
    if (outf) ((float4*)(outf + (size_t)row * 512))[tid] = y;
    if (outb) {
        bf16x4 o;
        o[0] = (bf16_t)y.x; o[1] = (bf16_t)y.y; o[2] = (bf16_t)y.z; o[3] = (bf16_t)y.w;
        *(bf16x4*)(outb + (size_t)row * 512 + tid * 4) = o;
    }
}

// ---------------- orchestration ----------------
// Workspace arena (29.5 MB high-water; lifetime-safe aliasing) — R6 layout (verified):
//   0- 2 MB : W1t    (A->F)
//   2- 4 MB : W2t    (A->G)
//   4-12 MB : Xb(4-8)+Eb(8-12) (A->B); then Opart splits 0-1 (D->D2); then out1b at 4-8 (E->H)
//  12-24 MB : QKVb   (B->D); then O f32 at 12-20 (D2->E); then Hb 12-28 (F->G)
//  24-28 MB : Vtb    (C->D); then Hb[12:16MB]   (F->G)
//  28-29.5  : Wqkvt  (A->B); then ml 1MB (4x32768 float2) (D->D2)
// d_out (16 MB arena view): Opart splits 2-3 in first 8 MB (D->D2); then FF f32 (G->H).
extern "C" void kernel_launch(void* const* d_in, const int* in_sizes, int n_in,
                              void* d_out, int out_size, void* d_ws, size_t ws_size,
                              hipStream_t stream)
{
    const float* inputs = (const float*)d_in[0];
    const float* encx   = (const float*)d_in[1];
    const float* Wq     = (const float*)d_in[2];
    const float* Wk     = (const float*)d_in[3];
    const float* Wv     = (const float*)d_in[4];
    const float* ln1g   = (const float*)d_in[5];
    const float* ln1b   = (const float*)d_in[6];
    const float* W1     = (const float*)d_in[7];
    const float* b1     = (const float*)d_in[8];
    const float* W2     = (const float*)d_in[9];
    const float* b2     = (const float*)d_in[10];
    const float* ln2g   = (const float*)d_in[11];
    const float* ln2b   = (const float*)d_in[12];

    char* ws = (char*)d_ws;
    const size_t MB = 1u << 20;
    bf16_t* W1t   = (bf16_t*)(ws);
    bf16_t* W2t   = (bf16_t*)(ws + 2 * MB);
    bf16_t* Xb    = (bf16_t*)(ws + 4 * MB);
    bf16_t* Op01  = (bf16_t*)(ws + 4 * MB);       // 8 MB, aliases Xb+Eb (dead after QKV gemm)
    bf16_t* out1b = (bf16_t*)(ws + 4 * MB);       // 4 MB, aliases Op01 (dead after combine)
    bf16_t* Eb    = (bf16_t*)(ws + 8 * MB);
    bf16_t* QKVb  = (bf16_t*)(ws + 12 * MB);
    float*  Obuf  = (float*)(ws + 12 * MB);       // 8 MB f32, aliases QKVb (dead after flash)
    bf16_t* Hb    = (bf16_t*)(ws + 12 * MB);      // 16 MB, aliases Obuf+Vtb
    bf16_t* Vtb   = (bf16_t*)(ws + 24 * MB);
    bf16_t* Wqkvt = (bf16_t*)(ws + 28 * MB);
    float2* mlbuf = (float2*)(ws + 28 * MB);      // 1 MB, aliases Wqkvt (dead after QKV gemm)
    bf16_t* Op23  = (bf16_t*)d_out;               // 8 MB, d_out unused until combine
    float*  FF    = (float*)d_out;                // FF (G->H, consumed in-place by ln2)

    // A. converts + weight transposes.  Q path folds 0.125 * log2(e) (exp2 domain).
    cvt_bf16_kernel<<<2048, 256, 0, stream>>>(inputs, Xb, 2097152, 0.125f * 1.44269504f);
    cvt_bf16_kernel<<<2048, 256, 0, stream>>>(encx, Eb, 2097152, 1.0f);
    wtrans_kernel<<<dim3(16, 16), 256, 0, stream>>>(Wq, Wqkvt,              512, 512);
    wtrans_kernel<<<dim3(16, 16), 256, 0, stream>>>(Wk, Wqkvt + 512 * 512,  512, 512);
    wtrans_kernel<<<dim3(16, 16), 256, 0, stream>>>(Wv, Wqkvt + 1024 * 512, 512, 512);
    wtrans_kernel<<<dim3(64, 16), 256, 0, stream>>>(W1, W1t, 512, 2048);
    wtrans_kernel<<<dim3(16, 64), 256, 0, stream>>>(W2, W2t, 2048, 512);
    // B. fused QKV projection: C[4096][1536]
    gemm_kernel<64, true, false, false, true><<<dim3(64, 12), 256, 0, stream>>>(
        Xb, Eb, 4, Wqkvt, nullptr, QKVb, 512, 1536);
    // C. V -> Vt[bh][64][2048]
    vtrans_kernel<<<dim3(32, 16), 256, 0, stream>>>(QKVb, Vtb);
    // D. flash attention (kv-split 4, swapped-QK 32x32) -> bf16 partials + (m,l)
    flash_kernel<<<dim3(16, 16, 4), 256, 0, stream>>>(QKVb, Vtb, Op01, Op23, mlbuf);
    // D2. combine partials -> O f32 [4096][512] (over dead QKVb)
    combine_kernel<<<8192, 256, 0, stream>>>(Op01, Op23, mlbuf, Obuf);
    // E. out1 = LN(O + inputs) -> bf16 only
    add_ln_kernel<false><<<4096, 128, 0, stream>>>(Obuf, inputs, ln1g, ln1b, nullptr, out1b);
    // F. H = relu(out1 @ W1 + b1)  [4096][2048] bf16
    gemm_kernel<128, false, true, true, true><<<dim3(32, 16), 256, 0, stream>>>(
        out1b, nullptr, 0, W1t, b1, Hb, 512, 2048);
    // G. FF = H @ W2 + b2  [4096][512] f32 -> d_out
    gemm_kernel<64, false, true, false, false><<<dim3(64, 4), 256, 0, stream>>>(
        Hb, nullptr, 0, W2t, b2, FF, 2048, 512);
    // H. final = LN(FF + out1b) -> d_out (in-place, row-local)
    add_ln_kernel<true><<<4096, 128, 0, stream>>>(FF, out1b, ln2g, ln2b, (float*)d_out, nullptr);
}